// Round 3
// baseline (105.056 us; speedup 1.0000x reference)
//
#include <hip/hip_runtime.h>
#include <math.h>

// Problem constants (S,N,B,T,D) = (8,8,2,2048,1024)
#define TPB 256

template <int CTRL>
__device__ __forceinline__ float dpp_add(float x) {
    int yi = __builtin_amdgcn_update_dpp(0, __float_as_int(x), CTRL, 0xF, 0xF, true);
    return x + __int_as_float(yi);
}

// Full 64-lane sum entirely on the VALU pipe (no LDS/bpermute):
// 4 DPP butterflies -> per-16-lane row sums; row_bcast15/31 chain -> lane 63
// holds the total; readlane broadcasts it as a wave-uniform value.
__device__ __forceinline__ float wave_sum(float x) {
    x = dpp_add<0xB1>(x);    // quad_perm [1,0,3,2] : xor 1
    x = dpp_add<0x4E>(x);    // quad_perm [2,3,0,1] : xor 2
    x = dpp_add<0x141>(x);   // row_half_mirror     : 4 -> 8-lane sums
    x = dpp_add<0x140>(x);   // row_mirror          : 8 -> 16-lane row sums
    x = dpp_add<0x142>(x);   // row_bcast15: lanes16-31 = r0+r1, 48-63 = r2+r3
    x = dpp_add<0x143>(x);   // row_bcast31: lanes48-63 = r0+r1+r2+r3
    return __int_as_float(__builtin_amdgcn_readlane(__float_as_int(x), 63));
}

__device__ __forceinline__ float dot4(const float4& a, const float4& b) {
    return a.x * b.x + a.y * b.y + a.z * b.z + a.w * b.w;
}

__global__ __launch_bounds__(TPB) void two_phase_attn_kernel(
    const float* __restrict__ q,    // [8][1024]
    const float* __restrict__ V,    // block_reps  [8][2][2048][1024]
    const float* __restrict__ P,    // partial_sums[8][2][2048][1024]
    const float* __restrict__ wgt,  // [1024]
    float* __restrict__ out)        // merged_out | merged_max | merged_lse
{
    constexpr int    N   = 8;
    constexpr int    D   = 1024;
    constexpr int    BT  = 4096;                 // B*T
    constexpr size_t ROW = (size_t)BT * D;       // 4194304
    constexpr size_t OUT_MM  = (size_t)8 * ROW;  // 33554432
    constexpr size_t OUT_LSE = OUT_MM + (size_t)BT * 8;
    constexpr float  SCALE = 0.03125f;           // 1/sqrt(1024)
    constexpr float  EPS   = 1e-6f;

    __shared__ float sV[N][D];                   // exactly 32768 B -> 5 blocks/CU

    const int bt   = blockIdx.x;
    const int tid  = threadIdx.x;
    const int w    = tid >> 6;
    const int lane = tid & 63;
    const int s0 = 2 * w, s1 = s0 + 1;           // wave owns s-pair == n-pair
    const size_t btD = (size_t)bt * D;

    // ---- Stage this wave's two V rows into LDS (coalesced float4) ----
    #pragma unroll
    for (int j = 0; j < 4; ++j) {
        const int d = j * 256 + lane * 4;
        *(float4*)(&sV[s0][d]) = *(const float4*)(V + (size_t)s0 * ROW + btD + d);
        *(float4*)(&sV[s1][d]) = *(const float4*)(V + (size_t)s1 * ROW + btD + d);
    }
    __syncthreads();

    // ---- Dot phase (j-outer): dots for 2 s-rows vs all 8 V rows, plus
    //      per-row sum-of-squares folded in (v already in registers) ----
    float dot0[N], dot1[N], vsq[N];
    #pragma unroll
    for (int n = 0; n < N; ++n) { dot0[n] = 0.f; dot1[n] = 0.f; vsq[n] = 0.f; }

    #pragma unroll
    for (int j = 0; j < 4; ++j) {
        const int d = j * 256 + lane * 4;
        const float4 wv = *(const float4*)(wgt + d);
        const float4 a  = *(const float4*)(q + s0 * D + d);
        const float4 b  = *(const float4*)(q + s1 * D + d);
        const float4 qa = make_float4(a.x*wv.x, a.y*wv.y, a.z*wv.z, a.w*wv.w);
        const float4 qb = make_float4(b.x*wv.x, b.y*wv.y, b.z*wv.z, b.w*wv.w);
        #pragma unroll
        for (int n = 0; n < N; ++n) {
            const float4 v = *(const float4*)(&sV[n][d]);
            dot0[n] += dot4(qa, v);
            dot1[n] += dot4(qb, v);
            vsq[n]  += dot4(v, v);
        }
    }

    // ---- Phase-2 P loads issued now; reductions below hide the latency ----
    float4 p0[4], p1[4];
    #pragma unroll
    for (int j = 0; j < 4; ++j) {
        const int d = j * 256 + lane * 4;
        p0[j] = *(const float4*)(P + (size_t)s0 * ROW + btD + d);
        p1[j] = *(const float4*)(P + (size_t)s1 * ROW + btD + d);
    }

    #pragma unroll
    for (int n = 0; n < N; ++n) {
        dot0[n] = wave_sum(dot0[n]);
        dot1[n] = wave_sum(dot1[n]);
        vsq[n]  = wave_sum(vsq[n]);
    }

    // ---- Phase 1 softmax over n (wave-uniform scalars) ----
    float e0[N], e1[N];
    float m0 = -1e30f, m1 = -1e30f;
    #pragma unroll
    for (int n = 0; n < N; ++n) {
        const float rinv = rsqrtf(vsq[n] * (1.0f / 1024.0f) + EPS);
        e0[n] = dot0[n] * rinv * SCALE;  m0 = fmaxf(m0, e0[n]);
        e1[n] = dot1[n] * rinv * SCALE;  m1 = fmaxf(m1, e1[n]);
    }
    float es0 = 0.f, es1 = 0.f;
    #pragma unroll
    for (int n = 0; n < N; ++n) {
        e0[n] = __expf(e0[n] - m0);  es0 += e0[n];
        e1[n] = __expf(e1[n] - m1);  es1 += e1[n];
    }

    // ---- Phase 2: rmsnorm(P) dot + merge scalars (q*w recomputed, L1-hot) ----
    float ssq20 = 0.f, ssq21 = 0.f, dp0 = 0.f, dp1 = 0.f;
    #pragma unroll
    for (int j = 0; j < 4; ++j) {
        const int d = j * 256 + lane * 4;
        const float4 wv = *(const float4*)(wgt + d);
        const float4 a  = *(const float4*)(q + s0 * D + d);
        const float4 b  = *(const float4*)(q + s1 * D + d);
        ssq20 += dot4(p0[j], p0[j]);
        ssq21 += dot4(p1[j], p1[j]);
        dp0 += (a.x*wv.x)*p0[j].x + (a.y*wv.y)*p0[j].y + (a.z*wv.z)*p0[j].z + (a.w*wv.w)*p0[j].w;
        dp1 += (b.x*wv.x)*p1[j].x + (b.y*wv.y)*p1[j].y + (b.z*wv.z)*p1[j].z + (b.w*wv.w)*p1[j].w;
    }
    ssq20 = wave_sum(ssq20);  ssq21 = wave_sum(ssq21);
    dp0   = wave_sum(dp0);    dp1   = wave_sum(dp1);

    const float im0 = dp0 * rsqrtf(ssq20 * (1.0f/1024.0f) + EPS) * SCALE;
    const float im1 = dp1 * rsqrtf(ssq21 * (1.0f/1024.0f) + EPS) * SCALE;

    const float mm0 = fmaxf(m0, im0),    mm1 = fmaxf(m1, im1);
    const float wi0 = __expf(m0 - mm0),  wi1 = __expf(m1 - mm1);
    const float wa0 = __expf(im0 - mm0), wa1 = __expf(im1 - mm1);
    const float lse0 = __logf(wi0 * es0 + wa0) + mm0;  // exp(inter_lse-inter_max)==es
    const float lse1 = __logf(wi1 * es1 + wa1) + mm1;
    const float nrm0 = wi0 + wa0,        nrm1 = wi1 + wa1;
    const float cA0 = wi0 / (es0 * nrm0), cA1 = wi1 / (es1 * nrm1);
    const float cp0 = wa0 / nrm0,         cp1 = wa1 / nrm1;

    // ---- Phase E (j-outer, low live-register count): inter_out + merge ----
    #pragma unroll
    for (int j = 0; j < 4; ++j) {
        const int d = j * 256 + lane * 4;
        float4 A0 = make_float4(0.f, 0.f, 0.f, 0.f);
        float4 A1 = make_float4(0.f, 0.f, 0.f, 0.f);
        #pragma unroll
        for (int n = 0; n < N; ++n) {
            const float4 v = *(const float4*)(&sV[n][d]);
            A0.x += e0[n]*v.x; A0.y += e0[n]*v.y; A0.z += e0[n]*v.z; A0.w += e0[n]*v.w;
            A1.x += e1[n]*v.x; A1.y += e1[n]*v.y; A1.z += e1[n]*v.z; A1.w += e1[n]*v.w;
        }
        float4 o0, o1;
        o0.x = cA0*A0.x + cp0*p0[j].x;  o0.y = cA0*A0.y + cp0*p0[j].y;
        o0.z = cA0*A0.z + cp0*p0[j].z;  o0.w = cA0*A0.w + cp0*p0[j].w;
        o1.x = cA1*A1.x + cp1*p1[j].x;  o1.y = cA1*A1.y + cp1*p1[j].y;
        o1.z = cA1*A1.z + cp1*p1[j].z;  o1.w = cA1*A1.w + cp1*p1[j].w;
        *(float4*)(out + (size_t)s0 * ROW + btD + d) = o0;
        *(float4*)(out + (size_t)s1 * ROW + btD + d) = o1;
    }
    if (lane == 0) {
        out[OUT_MM  + (size_t)s0 * BT + bt] = mm0;
        out[OUT_MM  + (size_t)s1 * BT + bt] = mm1;
        out[OUT_LSE + (size_t)s0 * BT + bt] = lse0;
        out[OUT_LSE + (size_t)s1 * BT + bt] = lse1;
    }
}

extern "C" void kernel_launch(void* const* d_in, const int* in_sizes, int n_in,
                              void* d_out, int out_size, void* d_ws, size_t ws_size,
                              hipStream_t stream) {
    const float* q   = (const float*)d_in[0];   // pseudo_queries [8,1024]
    const float* V   = (const float*)d_in[1];   // block_reps     [8,2,2048,1024]
    const float* P   = (const float*)d_in[2];   // partial_sums   [8,2,2048,1024]
    const float* wgt = (const float*)d_in[3];   // norm_weight    [1024]
    float* o = (float*)d_out;

    two_phase_attn_kernel<<<4096, TPB, 0, stream>>>(q, V, P, wgt, o);
}